// Round 4
// baseline (660.286 us; speedup 1.0000x reference)
//
#include <hip/hip_runtime.h>
#include <stdint.h>

#define HW 262144            // 512*512
#define ACQ_N 2097152        // 8*1*512*512

// hw-native transcendentals (1 instr each)
#define LOG2F(x) __builtin_amdgcn_logf(x)    // v_log_f32 = log2
#define EXP2F(x) __builtin_amdgcn_exp2f(x)   // v_exp_f32 = 2^x
#define SQRTF(x) __builtin_amdgcn_sqrtf(x)   // v_sqrt_f32
#define RCPF(x)  __builtin_amdgcn_rcpf(x)    // v_rcp_f32

// rotl via v_alignbit_b32 (guaranteed single instruction):
// alignbit(x,x,s) = rotr(x,s) ; rotl(x,r) = rotr(x,(32-r)&31)
#define ROTL(x, r) __builtin_amdgcn_alignbit((x), (x), (32 - (r)) & 31)

// ---------- host-side threefry2x32 for key derivation ----------
static inline void tf2x32_host(uint32_t k0, uint32_t k1, uint32_t c0, uint32_t c1,
                               uint32_t& o0, uint32_t& o1) {
  const uint32_t ks2 = k0 ^ k1 ^ 0x1BD11BDAu;
  uint32_t x0 = c0 + k0, x1 = c1 + k1;
#define TFR(r) { x0 += x1; x1 = (x1 << (r)) | (x1 >> (32 - (r))); x1 ^= x0; }
  TFR(13) TFR(15) TFR(26) TFR(6)
  x0 += k1;  x1 += ks2 + 1u;
  TFR(17) TFR(29) TFR(16) TFR(24)
  x0 += ks2; x1 += k0 + 2u;
  TFR(13) TFR(15) TFR(26) TFR(6)
  x0 += k0;  x1 += k1 + 3u;
  TFR(17) TFR(29) TFR(16) TFR(24)
  x0 += k1;  x1 += ks2 + 4u;
  TFR(13) TFR(15) TFR(26) TFR(6)
  x0 += ks2; x1 += k0 + 5u;
#undef TFR
  o0 = x0; o1 = x1;
}

// ---------- device: partitionable random_bits(32) for counter (0, idx) ----------
// out = o0 ^ o1 of threefry2x32(key, (0, idx)); c0=0 so x0 starts at k0.
__device__ __forceinline__ uint32_t rbits32(uint32_t k0, uint32_t k1, uint32_t idx) {
  const uint32_t ks2 = k0 ^ k1 ^ 0x1BD11BDAu;
  uint32_t x0 = k0, x1 = idx + k1;
#define TFR(r) { x0 += x1; x1 = ROTL(x1, r); x1 ^= x0; }
  TFR(13) TFR(15) TFR(26) TFR(6)
  x0 += k1;  x1 += ks2 + 1u;
  TFR(17) TFR(29) TFR(16) TFR(24)
  x0 += ks2; x1 += k0 + 2u;
  TFR(13) TFR(15) TFR(26) TFR(6)
  x0 += k0;  x1 += k1 + 3u;
  TFR(17) TFR(29) TFR(16) TFR(24)
  x0 += k1;  x1 += ks2 + 4u;
  TFR(13) TFR(15) TFR(26) TFR(6)
  x0 += ks2; x1 += k0 + 5u;
#undef TFR
  return x0 ^ x1;
}

__device__ __forceinline__ float unit_from_bits(uint32_t b) {
  return __uint_as_float((b >> 9) | 0x3F800000u) - 1.0f;
}

// z = sqrt(2)*erfinv(x), Giles poly, coeffs pre-scaled by sqrt(2).
// Far branch (w>=5, ~0.34% of samples) behind a real branch: ~80% of waves skip it.
__device__ __forceinline__ float sqrt2_erfinv(float x) {
  float ome = fmaf(-x, x, 1.0f);                 // 1-x^2, single rounding
  float l = LOG2F(ome);
  float w = -0.69314718056f * l;                 // -log1p(-x^2)
  float wn = w - 2.5f;
  float p = 3.974065e-08f;
  p = fmaf(p, wn, 4.854641e-07f);
  p = fmaf(p, wn, -4.982823e-06f);
  p = fmaf(p, wn, -6.210531e-06f);
  p = fmaf(p, wn, 3.091200e-04f);
  p = fmaf(p, wn, -1.773035e-03f);
  p = fmaf(p, wn, -5.908135e-03f);
  p = fmaf(p, wn, 3.488029e-01f);
  p = fmaf(p, wn, 2.123314e+00f);
  if (w >= 5.0f) {
    float wf = SQRTF(w) - 3.0f;
    float q = -2.831458e-04f;
    q = fmaf(q, wf, 1.427657e-04f);
    q = fmaf(q, wf, 1.908260e-03f);
    q = fmaf(q, wf, -5.195013e-03f);
    q = fmaf(q, wf, 8.116892e-03f);
    q = fmaf(q, wf, -1.0779791e-02f);
    q = fmaf(q, wf, 1.3348579e-02f);
    q = fmaf(q, wf, 1.416582e+00f);
    q = fmaf(q, wf, 4.006434e+00f);
    p = q;
  }
  return p * x;
}

// ws header: hdr[0]=ticket, hdr[1]=done, hdr[2..9]=float bias_acc[8]
__global__ __launch_bounds__(256) void acquire_fused(
    const float* __restrict__ inp, const int* __restrict__ frames,
    uint32_t* __restrict__ hdr, float* __restrict__ out,
    uint32_t ku0, uint32_t ku1, uint32_t kn0, uint32_t kn1) {
  __shared__ float s_bias;
  __shared__ uint32_t s_ticket;
  __shared__ float ws4[4];
  float* bias_acc = (float*)(hdr + 2);

  if (threadIdx.x == 0)
    s_ticket = __hip_atomic_fetch_add(&hdr[0], 1u, __ATOMIC_RELAXED,
                                      __HIP_MEMORY_SCOPE_AGENT);
  __syncthreads();
  uint32_t tick = s_ticket;                 // block-uniform

  // producer phase: first 512 arrivals compute the 512 chunk partial sums
  // of relu-mean's numerator for channel 1 (8 batches x 64 chunks)
  if (tick < 512u) {
    int pb = tick >> 6, chunk = tick & 63;
    const float* src = inp + ((size_t)pb * 5 + 1) * HW + (size_t)chunk * 4096;
    int t = threadIdx.x;
    float s = 0.0f;
#pragma unroll
    for (int k = 0; k < 16; ++k) s += src[t + k * 256];
    for (int off = 32; off; off >>= 1) s += __shfl_down(s, off);
    if ((t & 63) == 0) ws4[t >> 6] = s;
    __syncthreads();
    if (t == 0) {
      float tot = ws4[0] + ws4[1] + ws4[2] + ws4[3];
      __hip_atomic_fetch_add(&bias_acc[pb], tot, __ATOMIC_RELAXED,
                             __HIP_MEMORY_SCOPE_AGENT);
      __hip_atomic_fetch_add(&hdr[1], 1u, __ATOMIC_RELEASE,
                             __HIP_MEMORY_SCOPE_AGENT);
    }
  }

  int b = blockIdx.x >> 10;                 // 1024 blocks per batch
  int rem = ((blockIdx.x & 1023) << 8) | threadIdx.x;

  // per-pixel params (overlaps with other blocks' producer phase)
  const float* pb = inp + (size_t)b * 5 * HW;
  float img = pb[rem];
  float fw  = fmaxf(pb[2 * HW + rem], 0.0f);
  float fa  = fmaxf(pb[3 * HW + rem], 0.0f);
  float gw  = fmaxf(pb[4 * HW + rem], 0.0f);
  int nf = frames[b];                       // block-uniform

  // consumer phase: wait for all 512 partials, finalize bias
  if (threadIdx.x == 0) {
    while (__hip_atomic_load(&hdr[1], __ATOMIC_ACQUIRE,
                             __HIP_MEMORY_SCOPE_AGENT) != 512u)
      __builtin_amdgcn_s_sleep(2);
    float bs = __hip_atomic_load(&bias_acc[b], __ATOMIC_RELAXED,
                                 __HIP_MEMORY_SCOPE_AGENT);
    s_bias = fmaxf(bs * (1.0f / 262144.0f), 0.0f);
  }
  __syncthreads();
  float base = img + s_bias;

  float nfa = -fa;
  float fac = fa * 0.52876637294f;          // fa*log2(ln2), hoisted
  uint32_t idx = (uint32_t)(b * 16) * (uint32_t)HW + (uint32_t)rem;

  float acc = 0.0f;
  for (int f = 0; f < nf; ++f) {
    uint32_t ub = rbits32(ku0, ku1, idx);
    uint32_t nb = rbits32(kn0, kn1, idx);
    idx += (uint32_t)HW;

    // t^(-fa), t=-ln u:  exp2(-fa*log2(-log2(u)) + fa*log2(ln2))
    float u = unit_from_bits(ub);
    u = fminf(fmaxf(u, 1e-6f), 0.999999f);  // v_med3
    float l2u = LOG2F(u);                   // < 0
    float pw = EXP2F(fmaf(nfa, LOG2F(-l2u), fac));

    // normal: u2 in [-0.99999994, 0.99999994] by construction (no clamp)
    float z = sqrt2_erfinv(fmaf(unit_from_bits(nb), 2.0f, -0.99999994f));
    float s = fmaf(gw, z, fmaf(fw, pw, base));
    acc += fminf(fmaxf(s, 0.0f), 1.0f);     // v_med3
  }
  out[(size_t)b * HW + rem] = acc * RCPF((float)nf);

  // center = clip(base + fw*(1/(fa+1))^fa, 0, 1)
  float cpw = EXP2F(nfa * LOG2F(fa + 1.0f));
  out[ACQ_N + (size_t)b * HW + rem] = fminf(fmaxf(fmaf(fw, cpw, base), 0.0f), 1.0f);
}

extern "C" void kernel_launch(void* const* d_in, const int* in_sizes, int n_in,
                              void* d_out, int out_size, void* d_ws, size_t ws_size,
                              hipStream_t stream) {
  const float* inp    = (const float*)d_in[0];
  const int*   frames = (const int*)d_in[1];
  float* out = (float*)d_out;
  uint32_t* hdr = (uint32_t*)d_ws;   // 10 u32: ticket, done, bias_acc[8]

  // jax_threefry_partitionable=True: split(key(42)) foldlike:
  // ku = cipher((0,42),(0,0)), kn = cipher((0,42),(0,1))
  uint32_t ku0, ku1, kn0, kn1;
  tf2x32_host(0u, 42u, 0u, 0u, ku0, ku1);
  tf2x32_host(0u, 42u, 0u, 1u, kn0, kn1);

  hipMemsetAsync(hdr, 0, 64, stream);  // zero ticket/done/bias_acc (graph-capturable)
  acquire_fused<<<dim3(8192), dim3(256), 0, stream>>>(inp, frames, hdr, out,
                                                      ku0, ku1, kn0, kn1);
}

// Round 5
// 191.239 us; speedup vs baseline: 3.4527x; 3.4527x over previous
//
#include <hip/hip_runtime.h>
#include <stdint.h>

#define HW 262144            // 512*512
#define ACQ_N 2097152        // 8*1*512*512

// hw-native transcendentals (1 instr each, quarter-rate)
#define LOG2F(x) __builtin_amdgcn_logf(x)    // v_log_f32 = log2
#define EXP2F(x) __builtin_amdgcn_exp2f(x)   // v_exp_f32 = 2^x
#define SQRTF(x) __builtin_amdgcn_sqrtf(x)   // v_sqrt_f32
#define RCPF(x)  __builtin_amdgcn_rcpf(x)    // v_rcp_f32

// rotl via v_alignbit_b32 (single instruction): alignbit(x,x,s)=rotr(x,s)
#define ROTL(x, r) __builtin_amdgcn_alignbit((x), (x), (32 - (r)) & 31)

// ---------- host-side threefry2x32 for key derivation ----------
static inline void tf2x32_host(uint32_t k0, uint32_t k1, uint32_t c0, uint32_t c1,
                               uint32_t& o0, uint32_t& o1) {
  const uint32_t ks2 = k0 ^ k1 ^ 0x1BD11BDAu;
  uint32_t x0 = c0 + k0, x1 = c1 + k1;
#define TFR(r) { x0 += x1; x1 = (x1 << (r)) | (x1 >> (32 - (r))); x1 ^= x0; }
  TFR(13) TFR(15) TFR(26) TFR(6)
  x0 += k1;  x1 += ks2 + 1u;
  TFR(17) TFR(29) TFR(16) TFR(24)
  x0 += ks2; x1 += k0 + 2u;
  TFR(13) TFR(15) TFR(26) TFR(6)
  x0 += k0;  x1 += k1 + 3u;
  TFR(17) TFR(29) TFR(16) TFR(24)
  x0 += k1;  x1 += ks2 + 4u;
  TFR(13) TFR(15) TFR(26) TFR(6)
  x0 += ks2; x1 += k0 + 5u;
#undef TFR
  o0 = x0; o1 = x1;
}

// device: partitionable random_bits(32) for counter (0, idx): o0^o1
__device__ __forceinline__ uint32_t rbits32(uint32_t k0, uint32_t k1, uint32_t idx) {
  const uint32_t ks2 = k0 ^ k1 ^ 0x1BD11BDAu;
  uint32_t x0 = k0, x1 = idx + k1;
#define TFR(r) { x0 += x1; x1 = ROTL(x1, r); x1 ^= x0; }
  TFR(13) TFR(15) TFR(26) TFR(6)
  x0 += k1;  x1 += ks2 + 1u;
  TFR(17) TFR(29) TFR(16) TFR(24)
  x0 += ks2; x1 += k0 + 2u;
  TFR(13) TFR(15) TFR(26) TFR(6)
  x0 += k0;  x1 += k1 + 3u;
  TFR(17) TFR(29) TFR(16) TFR(24)
  x0 += k1;  x1 += ks2 + 4u;
  TFR(13) TFR(15) TFR(26) TFR(6)
  x0 += ks2; x1 += k0 + 5u;
#undef TFR
  return x0 ^ x1;
}

__device__ __forceinline__ float unit_from_bits(uint32_t b) {
  return __uint_as_float((b >> 9) | 0x3F800000u) - 1.0f;
}

// z = sqrt(2)*erfinv(x), Giles poly, coeffs pre-scaled by sqrt(2).
// Far branch (w>=5, ~0.34% of draws) behind a real branch.
__device__ __forceinline__ float sqrt2_erfinv(float x) {
  float ome = fmaf(-x, x, 1.0f);                 // 1-x^2, single rounding
  float w = -0.69314718056f * LOG2F(ome);        // -log1p(-x^2)
  float wn = w - 2.5f;
  float p = 3.974065e-08f;
  p = fmaf(p, wn, 4.854641e-07f);
  p = fmaf(p, wn, -4.982823e-06f);
  p = fmaf(p, wn, -6.210531e-06f);
  p = fmaf(p, wn, 3.091200e-04f);
  p = fmaf(p, wn, -1.773035e-03f);
  p = fmaf(p, wn, -5.908135e-03f);
  p = fmaf(p, wn, 3.488029e-01f);
  p = fmaf(p, wn, 2.123314e+00f);
  if (__builtin_expect(w >= 5.0f, 0)) {
    float wf = SQRTF(w) - 3.0f;
    float q = -2.831458e-04f;
    q = fmaf(q, wf, 1.427657e-04f);
    q = fmaf(q, wf, 1.908260e-03f);
    q = fmaf(q, wf, -5.195013e-03f);
    q = fmaf(q, wf, 8.116892e-03f);
    q = fmaf(q, wf, -1.0779791e-02f);
    q = fmaf(q, wf, 1.3348579e-02f);
    q = fmaf(q, wf, 1.416582e+00f);
    q = fmaf(q, wf, 4.006434e+00f);
    p = q;
  }
  return p * x;
}

// ---------- bias partial sums: relu(mean(inp[:,1])) stage 1 ----------
__global__ __launch_bounds__(256) void bias_partial(const float* __restrict__ inp,
                                                    float* __restrict__ partial) {
  int blk = blockIdx.x;                 // 512 blocks: 8 batches x 64 chunks
  int b = blk >> 6, chunk = blk & 63;
  const float4* src = (const float4*)(inp + ((size_t)b * 5 + 1) * HW
                                          + (size_t)chunk * 4096);
  int t = threadIdx.x;
  float s = 0.0f;
#pragma unroll
  for (int k = 0; k < 4; ++k) {
    float4 v = src[t + k * 256];
    s += (v.x + v.y) + (v.z + v.w);
  }
  for (int off = 32; off; off >>= 1) s += __shfl_down(s, off);
  __shared__ float ws4[4];
  if ((t & 63) == 0) ws4[t >> 6] = s;
  __syncthreads();
  if (t == 0) partial[blk] = ws4[0] + ws4[1] + ws4[2] + ws4[3];
}

// ---------- main: one thread per output pixel; bias finalized in-block ----------
__global__ __launch_bounds__(256) void acquire_main(
    const float* __restrict__ inp, const int* __restrict__ frames,
    const float* __restrict__ partial, float* __restrict__ out,
    uint32_t ku0, uint32_t ku1, uint32_t kn0, uint32_t kn1) {
  int b = blockIdx.x >> 10;                         // 1024 blocks per batch
  int rem = ((blockIdx.x & 1023) << 8) | threadIdx.x;

  // finalize bias for this batch from the 64 partial sums (wave 0 only)
  __shared__ float s_bias;
  if (threadIdx.x < 64) {
    float s = partial[(b << 6) | threadIdx.x];
    for (int off = 32; off; off >>= 1) s += __shfl_down(s, off);
    if (threadIdx.x == 0) s_bias = fmaxf(s * (1.0f / 262144.0f), 0.0f);
  }

  const float* pb = inp + (size_t)b * 5 * HW;
  float img = pb[rem];
  float fw  = fmaxf(pb[2 * HW + rem], 0.0f);
  float fa  = fmaxf(pb[3 * HW + rem], 0.0f);
  float gw  = fmaxf(pb[4 * HW + rem], 0.0f);
  __syncthreads();
  float base = img + s_bias;

  int nf = frames[b];                               // block-uniform
  float nfa = -fa;
  float fac = fa * 0.52876637294f;                  // fa*log2(ln2), hoisted
  uint32_t idx = (uint32_t)(b * 16) * (uint32_t)HW + (uint32_t)rem;

  float acc = 0.0f;
#pragma unroll 2
  for (int f = 0; f < nf; ++f) {
    uint32_t ub = rbits32(ku0, ku1, idx);
    uint32_t nb = rbits32(kn0, kn1, idx);
    idx += (uint32_t)HW;

    // t^(-fa), t=-ln u: exp2(-fa*log2(-log2(u)) + fa*log2(ln2))
    float u = unit_from_bits(ub);
    u = fminf(fmaxf(u, 1e-6f), 0.999999f);          // v_med3
    float l2u = LOG2F(u);                           // < 0
    float pw = EXP2F(fmaf(nfa, LOG2F(-l2u), fac));

    // normal draw: u2 in [-0.99999994, 0.99999994] by construction
    float z = sqrt2_erfinv(fmaf(unit_from_bits(nb), 2.0f, -0.99999994f));
    float s = fmaf(gw, z, fmaf(fw, pw, base));
    acc += fminf(fmaxf(s, 0.0f), 1.0f);             // v_med3
  }
  out[(size_t)b * HW + rem] = acc * RCPF((float)nf);

  // center = clip(base + fw*(1/(fa+1))^fa, 0, 1)
  float cpw = EXP2F(nfa * LOG2F(fa + 1.0f));
  out[ACQ_N + (size_t)b * HW + rem] = fminf(fmaxf(fmaf(fw, cpw, base), 0.0f), 1.0f);
}

extern "C" void kernel_launch(void* const* d_in, const int* in_sizes, int n_in,
                              void* d_out, int out_size, void* d_ws, size_t ws_size,
                              hipStream_t stream) {
  const float* inp    = (const float*)d_in[0];
  const int*   frames = (const int*)d_in[1];
  float* out = (float*)d_out;
  float* partial = (float*)d_ws;   // 512 floats

  // jax_threefry_partitionable=True: split(key(42)) foldlike:
  // ku = cipher((0,42),(0,0)), kn = cipher((0,42),(0,1))
  uint32_t ku0, ku1, kn0, kn1;
  tf2x32_host(0u, 42u, 0u, 0u, ku0, ku1);
  tf2x32_host(0u, 42u, 0u, 1u, kn0, kn1);

  bias_partial<<<dim3(512), dim3(256), 0, stream>>>(inp, partial);
  acquire_main<<<dim3(8192), dim3(256), 0, stream>>>(inp, frames, partial, out,
                                                     ku0, ku1, kn0, kn1);
}